// Round 1
// baseline (971.901 us; speedup 1.0000x reference)
//
#include <hip/hip_runtime.h>

typedef _Float16 f16;
typedef unsigned short u16;
typedef unsigned int u32;
typedef _Float16 f16x8 __attribute__((ext_vector_type(8)));
typedef float f32x4 __attribute__((ext_vector_type(4)));

union F16x8U { f16x8 v; uint4 q; u16 us[8]; f16 h[8]; };
union HBits { f16 f; u16 u; };

#define GLD16(g, l)                                                        \
  __builtin_amdgcn_global_load_lds(                                        \
      (const __attribute__((address_space(1))) void*)(g),                  \
      (__attribute__((address_space(3))) void*)(l), 16, 0, 0)

// ---------------------------------------------------------------- converts
__global__ void kcvt_x(const float* __restrict__ x, f16* __restrict__ xo) {
  int i = (blockIdx.x * 256 + threadIdx.x) << 3;  // 8 elems/thread
  float4 a = *(const float4*)(x + i);
  float4 b = *(const float4*)(x + i + 4);
  F16x8U u;
  u.h[0] = (f16)a.x; u.h[1] = (f16)a.y; u.h[2] = (f16)a.z; u.h[3] = (f16)a.w;
  u.h[4] = (f16)b.x; u.h[5] = (f16)b.y; u.h[6] = (f16)b.z; u.h[7] = (f16)b.w;
  *(uint4*)(xo + i) = u.q;
}

__global__ void kcvt_wpre(const float* __restrict__ w, f16* __restrict__ wo) {
  int e = (blockIdx.x * 256 + threadIdx.x) << 2;  // [576][512] out
  int row = e >> 9, col = e & 511;
  union { uint2 q; f16 h[4]; } u;
  if (row < 513) {
    float4 v = *(const float4*)(w + (size_t)row * 512 + col);
    u.h[0] = (f16)v.x; u.h[1] = (f16)v.y; u.h[2] = (f16)v.z; u.h[3] = (f16)v.w;
  } else {
    u.h[0] = u.h[1] = u.h[2] = u.h[3] = (f16)0.0f;
  }
  *(uint2*)(wo + e) = u.q;
}

__global__ void kcvt_rw(const float* __restrict__ rwsrc, f16* __restrict__ ro) {
  int e = (blockIdx.x * 256 + threadIdx.x) << 2;  // [128][576] out
  int row = e / 576, c0 = e - row * 576;
  union { uint2 q; f16 h[4]; } u;
#pragma unroll
  for (int i = 0; i < 4; ++i) {
    int c = c0 + i;
    float v = (row < 127 && c < 513) ? rwsrc[(size_t)row * 513 + c] : 0.0f;
    u.h[i] = (f16)v;
  }
  *(uint2*)(ro + e) = u.q;
}

// W_pack [32768][544] fp16: col<513 = W_leaf, col 513 = b_leaf, rest 0
__global__ void kcvt_wleaf(const float* __restrict__ wl, const float* __restrict__ bl,
                           f16* __restrict__ wo) {
  int e = (blockIdx.x * 256 + threadIdx.x) << 3;
  int row = e / 544, c0 = e - row * 544;
  const float* src = wl + (size_t)row * 513 + c0;
  F16x8U u;
#pragma unroll
  for (int i = 0; i < 8; ++i) {
    int c = c0 + i;
    float v = (c < 513) ? src[i] : ((c == 513) ? bl[row] : 0.0f);
    u.h[i] = (f16)v;
  }
  *(uint4*)(wo + e) = u.q;
}

// ---------------------------------------------------- generic 128x64 GEMM-BT
// MODE 0: h = relu(x@Wpre^T + b), f16 out stride 576, col513 := 1.0
// MODE 1: G = h@rw^T, f32 out stride 128
template <int MODE>
__global__ __launch_bounds__(256, 2) void kgemm(
    const f16* __restrict__ A, const f16* __restrict__ B,
    const float* __restrict__ bias, void* __restrict__ C,
    int NK, int astr, int bstr) {
  __shared__ alignas(16) f16 al[2][128 * 32];
  __shared__ alignas(16) f16 bl[2][64 * 40];
  const int tid = threadIdx.x, lane = tid & 63, wid = tid >> 6;
  const int wm = wid >> 1, wn = wid & 1;
  const int brow = blockIdx.x << 7, bcol = blockIdx.y << 6;

  int arow[2], aseg[2];
#pragma unroll
  for (int i = 0; i < 2; ++i) { int c = i * 256 + tid; arow[i] = c >> 2; aseg[i] = c & 3; }
  int br0 = tid / 5, bs0 = tid - br0 * 5;
  int c1 = 256 + lane;
  int br1 = c1 / 5, bs1 = c1 - br1 * 5;

  f32x4 acc[4][2];
#pragma unroll
  for (int mf = 0; mf < 4; ++mf)
#pragma unroll
    for (int nf = 0; nf < 2; ++nf)
#pragma unroll
      for (int j = 0; j < 4; ++j) acc[mf][nf][j] = 0.0f;

  auto stage = [&](int kc, int bf) {
    int kcol = kc << 5;
#pragma unroll
    for (int i = 0; i < 2; ++i) {
      f16* ldsb = &al[bf][(i * 256 + (wid << 6)) << 3];
      GLD16(A + (size_t)(brow + arow[i]) * astr + kcol + (aseg[i] << 3), ldsb);
    }
    {
      f16* ldsb = &bl[bf][(wid << 6) << 3];
      GLD16(B + (size_t)(bcol + br0) * bstr + kcol + (bs0 < 4 ? (bs0 << 3) : 0), ldsb);
    }
    if (wid == 0) {
      f16* ldsb = &bl[bf][256 << 3];
      GLD16(B + (size_t)(bcol + br1) * bstr + kcol + (bs1 < 4 ? (bs1 << 3) : 0), ldsb);
    }
  };

  stage(0, 0);
  __syncthreads();
  int cur = 0;
  for (int kc = 0; kc < NK; ++kc) {
    if (kc + 1 < NK) stage(kc + 1, cur ^ 1);
    f16x8 af[4], bfm[2];
#pragma unroll
    for (int mf = 0; mf < 4; ++mf)
      af[mf] = *(const f16x8*)&al[cur][((wm << 6) + (mf << 4) + (lane & 15)) * 32 + ((lane >> 4) << 3)];
#pragma unroll
    for (int nf = 0; nf < 2; ++nf)
      bfm[nf] = *(const f16x8*)&bl[cur][((wn << 5) + (nf << 4) + (lane & 15)) * 40 + ((lane >> 4) << 3)];
#pragma unroll
    for (int mf = 0; mf < 4; ++mf)
#pragma unroll
      for (int nf = 0; nf < 2; ++nf)
        acc[mf][nf] = __builtin_amdgcn_mfma_f32_16x16x32_f16(af[mf], bfm[nf], acc[mf][nf], 0, 0, 0);
    __syncthreads();
    cur ^= 1;
  }

#pragma unroll
  for (int mf = 0; mf < 4; ++mf) {
#pragma unroll
    for (int nf = 0; nf < 2; ++nf) {
      int gcol = bcol + (wn << 5) + (nf << 4) + (lane & 15);
      int gr0 = brow + (wm << 6) + (mf << 4) + ((lane >> 4) << 2);
      if (MODE == 0) {
        float bv = (gcol < 513) ? bias[gcol] : 0.0f;
#pragma unroll
        for (int j = 0; j < 4; ++j) {
          float v = fmaxf(acc[mf][nf][j] + bv, 0.0f);
          ((f16*)C)[(size_t)(gr0 + j) * 576 + gcol] = (gcol == 513) ? (f16)1.0f : (f16)v;
        }
      } else {
#pragma unroll
        for (int j = 0; j < 4; ++j)
          ((float*)C)[(size_t)(gr0 + j) * 128 + gcol] = acc[mf][nf][j];
      }
    }
  }
}

// ---------------------------------------------------------------- norms
__global__ void khnorm(const f16* __restrict__ hf, float* __restrict__ ihn) {
  int row = (blockIdx.x << 2) + (threadIdx.x >> 6);
  int lane = threadIdx.x & 63;
  float s = 0.0f;
  for (int c = lane; c < 513; c += 64) {
    float v = (float)hf[(size_t)row * 576 + c];
    s += v * v;
  }
  for (int o = 32; o; o >>= 1) s += __shfl_down(s, o);
  if (!lane) ihn[row] = 1.0f / fmaxf(sqrtf(s), 1e-12f);
}

__global__ void kinvrw(const float* __restrict__ rw, float* __restrict__ irw) {
  int j = (blockIdx.x << 2) + (threadIdx.x >> 6);
  if (j >= 127) return;
  int lane = threadIdx.x & 63;
  float s = 0.0f;
  for (int d = lane; d < 513; d += 64) {
    float v = rw[(size_t)j * 513 + d];
    s += v * v;
  }
  for (int o = 32; o; o >>= 1) s += __shfl_down(s, o);
  if (!lane) irw[j] = 1.0f / fmaxf(sqrtf(s), 1e-12f);
}

// ------------------------------------------------------------- routing/softmax
// per-sample tree walk; writes s_w as fp16 in block-permuted layout
// swh[l*8192 + (b&~127) + ((b&15)<<3) + ((b>>4)&7)]
__global__ void kroute(const float* __restrict__ G, const float* __restrict__ ihn,
                       const float* __restrict__ irw, u16* __restrict__ swh,
                       float* __restrict__ entp) {
  int b = blockIdx.x * 256 + threadIdx.x;
  float ih = ihn[b];
  const float* g = G + (size_t)b * 128;
  float ent = 0.0f;
  size_t wbase = (size_t)(b & ~127) + (((size_t)b & 15) << 3) + ((b >> 4) & 7);
  for (int l = 0; l < 128; ++l) {
    int n = 0;
    float lp = 0.0f;
#pragma unroll
    for (int k = 6; k >= 0; --k) {
      int bit = (l >> k) & 1;
      float cs = g[n] * ih * irw[n];
      float pr = bit ? 0.5f * (1.0f - cs) : 0.5f * (1.0f + cs);
      pr = fminf(fmaxf(pr, 0.01f), 0.99f);
      lp += __logf(pr);
      n = 2 * n + 1 + bit;
    }
    float sw = __expf(lp);
    ent -= sw * lp;
    HBits hb; hb.f = (f16)sw;
    swh[(size_t)l * 8192 + wbase] = hb.u;
  }
  for (int o = 32; o; o >>= 1) ent += __shfl_down(ent, o);
  __shared__ float red[4];
  if (!(threadIdx.x & 63)) red[threadIdx.x >> 6] = ent;
  __syncthreads();
  if (!threadIdx.x) atomicAdd(entp, red[0] + red[1] + red[2] + red[3]);
}

// ------------------------------------------------------------------ big GEMM
// out[b,o] = scale * sum_l sum_k (s_w[l,b]*h[b,k]) * Wpack[l*256+o, k]
// 128x64 tile, 4 waves each 128x16 (MF=8). A in regs (reused across leaves),
// B streamed via global_load_lds, 3-buffer depth-2, counted vmcnt.
__global__ __launch_bounds__(256, 1) void kbig(
    const f16* __restrict__ hf, const f16* __restrict__ wp,
    const u16* __restrict__ swh, const float* __restrict__ entp,
    float* __restrict__ out) {
  __shared__ alignas(16) u16 slds[16384];        // 32 KB s_w slab
  __shared__ alignas(16) f16 blds[3][10240];     // 3 x 20 KB (4 leaves x 64 x 40)

  const int tid = threadIdx.x;
  const int lane = tid & 63, wid = tid >> 6;
  const int lid = blockIdx.x;                    // XCD-aware: 2 XCDs per o-tile
  const int ob = (lid & 7) >> 1;
  const int mb = ((lid >> 3) << 1) | (lid & 1);
  const int brow = mb << 7;
  const int ocol = ob << 6;

  // stage s_w slab (2048 x 16B)
  for (int it = 0; it < 8; ++it) {
    int c = it * 256 + tid;
    int e = c << 3;
    int l = e >> 7, q = e & 127;
    u16* ldsb = &slds[(it * 256 + (wid << 6)) << 3];
    GLD16(swh + ((size_t)l << 13) + brow + q, ldsb);
  }

  // B-stage per-thread coords (5 chunks of 16B per thread per step)
  int rowoff[5], segoff[5];
#pragma unroll
  for (int i = 0; i < 5; ++i) {
    int c = i * 256 + tid;
    int ls = c / 320;
    int rem = c - ls * 320;
    int r = rem / 5;
    int sg = rem - r * 5;
    rowoff[i] = ls * 256 + ocol + r;
    segoff[i] = (sg < 4) ? (sg << 3) : 0;  // seg 4 = row pad, load dummy col 0
  }

  f32x4 acc[8];
#pragma unroll
  for (int mf = 0; mf < 8; ++mf)
#pragma unroll
    for (int j = 0; j < 4; ++j) acc[mf][j] = 0.0f;

  auto stageB = [&](int s, int bf) {
    const int kcol = (s >> 5) << 5;
    const int l0r = ((s & 31) << 2) * 256;
    f16* bb = blds[bf];
#pragma unroll
    for (int i = 0; i < 5; ++i) {
      f16* ldsb = bb + ((i * 256 + (wid << 6)) << 3);
      GLD16(wp + (size_t)(l0r + rowoff[i]) * 544 + kcol + segoff[i], ldsb);
    }
  };

  stageB(0, 0);
  stageB(1, 1);

  f16x8 afr[8];
  int cur = 0;
  const f16* abase = hf + (size_t)(brow + (lane & 15)) * 576 + ((lane >> 4) << 3);
  const int boff = (wid * 16 + (lane & 15)) * 40 + ((lane >> 4) << 3);
  const int soff = (lane & 15) << 3;

  for (int s = 0; s < 544; ++s) {
    int nb = cur + 2; if (nb >= 3) nb -= 3;
    if (s + 2 < 544) stageB(s + 2, nb);
    if (s < 542)       asm volatile("s_waitcnt vmcnt(10)" ::: "memory");
    else if (s == 542) asm volatile("s_waitcnt vmcnt(5)" ::: "memory");
    else               asm volatile("s_waitcnt vmcnt(0)" ::: "memory");
    __builtin_amdgcn_s_barrier();
    __builtin_amdgcn_sched_barrier(0);

    const int kc = s >> 5, lg = s & 31;
    if (lg == 0) {  // new k-chunk: reload A fragments (registers, reused 32 steps)
      const f16* ap = abase + (kc << 5);
#pragma unroll
      for (int mf = 0; mf < 8; ++mf)
        afr[mf] = *(const f16x8*)(ap + (size_t)(mf << 4) * 576);
    }

    const f16* bb = blds[cur];
#pragma unroll
    for (int ls = 0; ls < 4; ++ls) {
      int l = (lg << 2) + ls;
      f16x8 bfr = *(const f16x8*)(bb + ls * 2560 + boff);
      uint4 sq = *(const uint4*)(&slds[(l << 7) + soff]);
      u32 dw[4] = {sq.x, sq.y, sq.z, sq.w};
#pragma unroll
      for (int mf = 0; mf < 8; ++mf) {
        u32 d = dw[mf >> 1];
        HBits hb; hb.u = (mf & 1) ? (u16)(d >> 16) : (u16)(d & 0xffffu);
        f16x8 as = afr[mf] * hb.f;  // fold s_w[l,row] into A fragment
        acc[mf] = __builtin_amdgcn_mfma_f32_16x16x32_f16(as, bfr, acc[mf], 0, 0, 0);
      }
    }
    __builtin_amdgcn_sched_barrier(0);
    __builtin_amdgcn_s_barrier();
    cur = cur + 1; if (cur >= 3) cur = 0;
  }

  float ent = *entp;
  float scale = 1.0f + ent / (8192.0f * (128.0f / 6.0f) * logf(6.0f));
  const int cc = ocol + (wid << 4) + (lane & 15);
#pragma unroll
  for (int mf = 0; mf < 8; ++mf) {
    int r0 = brow + (mf << 4) + ((lane >> 4) << 2);
#pragma unroll
    for (int j = 0; j < 4; ++j)
      out[(size_t)(r0 + j) * 256 + cc] = scale * acc[mf][j];
  }
}

// ------------------------------------------------------------------- launch
extern "C" void kernel_launch(void* const* d_in, const int* in_sizes, int n_in,
                              void* d_out, int out_size, void* d_ws, size_t ws_size,
                              hipStream_t stream) {
  const float* x     = (const float*)d_in[0];
  const float* wpre  = (const float*)d_in[1];
  const float* bpre  = (const float*)d_in[2];
  const float* rw    = (const float*)d_in[3];
  const float* wleaf = (const float*)d_in[4];
  const float* bleaf = (const float*)d_in[5];
  float* out = (float*)d_out;

  char* ws = (char*)d_ws;
  constexpr size_t O_ENT = 0;
  constexpr size_t O_XO  = 256;                     // x fp16 [8192][512]
  constexpr size_t O_WPO = O_XO  + 8388608;         // Wpre fp16 [576][512]
  constexpr size_t O_RWO = O_WPO + 589824;          // rw fp16 [128][576]
  constexpr size_t O_IRW = O_RWO + 147456;          // 1/||rw|| [128]
  constexpr size_t O_HO  = O_IRW + 512;             // h fp16 [8192][576]
  constexpr size_t O_IHN = O_HO  + 9437184;         // 1/||h|| [8192]
  constexpr size_t O_G   = O_IHN + 32768;           // G f32 [8192][128]
  constexpr size_t O_SWH = O_G   + 4194304;         // s_w fp16 perm [128][8192]
  constexpr size_t O_WPK = O_SWH + 2097152;         // Wpack fp16 [32768][544]

  float* ent = (float*)(ws + O_ENT);
  f16* xo   = (f16*)(ws + O_XO);
  f16* wpo  = (f16*)(ws + O_WPO);
  f16* rwo  = (f16*)(ws + O_RWO);
  float* irw = (float*)(ws + O_IRW);
  f16* ho   = (f16*)(ws + O_HO);
  float* ihn = (float*)(ws + O_IHN);
  float* go = (float*)(ws + O_G);
  u16* swh  = (u16*)(ws + O_SWH);
  f16* wpk  = (f16*)(ws + O_WPK);

  hipMemsetAsync(ent, 0, sizeof(float), stream);
  kcvt_x<<<2048, 256, 0, stream>>>(x, xo);
  kcvt_wpre<<<288, 256, 0, stream>>>(wpre, wpo);
  kcvt_rw<<<72, 256, 0, stream>>>(rw, rwo);
  kcvt_wleaf<<<8704, 256, 0, stream>>>(wleaf, bleaf, wpk);
  kgemm<0><<<dim3(64, 9), 256, 0, stream>>>(xo, wpo, bpre, (void*)ho, 16, 512, 512);
  khnorm<<<2048, 256, 0, stream>>>(ho, ihn);
  kinvrw<<<32, 256, 0, stream>>>(rw, irw);
  kgemm<1><<<dim3(64, 2), 256, 0, stream>>>(ho, rwo, nullptr, (void*)go, 17, 576, 576);
  kroute<<<32, 256, 0, stream>>>(go, ihn, irw, swh, ent);
  kbig<<<256, 256, 0, stream>>>(ho, wpk, swh, ent, out);
}

// Round 2
// 691.358 us; speedup vs baseline: 1.4058x; 1.4058x over previous
//
#include <hip/hip_runtime.h>

typedef _Float16 f16;
typedef unsigned short u16;
typedef unsigned int u32;
typedef _Float16 f16x8 __attribute__((ext_vector_type(8)));
typedef float f32x4 __attribute__((ext_vector_type(4)));

union F16x8U { f16x8 v; uint4 q; u16 us[8]; f16 h[8]; };
union HBits { f16 f; u16 u; };

#define GLD16(g, l)                                                        \
  __builtin_amdgcn_global_load_lds(                                        \
      (const __attribute__((address_space(1))) void*)(g),                  \
      (__attribute__((address_space(3))) void*)(l), 16, 0, 0)

// ---------------------------------------------------------------- converts
__global__ void kcvt_x(const float* __restrict__ x, f16* __restrict__ xo) {
  int i = (blockIdx.x * 256 + threadIdx.x) << 3;  // 8 elems/thread
  float4 a = *(const float4*)(x + i);
  float4 b = *(const float4*)(x + i + 4);
  F16x8U u;
  u.h[0] = (f16)a.x; u.h[1] = (f16)a.y; u.h[2] = (f16)a.z; u.h[3] = (f16)a.w;
  u.h[4] = (f16)b.x; u.h[5] = (f16)b.y; u.h[6] = (f16)b.z; u.h[7] = (f16)b.w;
  *(uint4*)(xo + i) = u.q;
}

__global__ void kcvt_wpre(const float* __restrict__ w, f16* __restrict__ wo) {
  int e = (blockIdx.x * 256 + threadIdx.x) << 2;  // [576][512] out
  int row = e >> 9, col = e & 511;
  union { uint2 q; f16 h[4]; } u;
  if (row < 513) {
    float4 v = *(const float4*)(w + (size_t)row * 512 + col);
    u.h[0] = (f16)v.x; u.h[1] = (f16)v.y; u.h[2] = (f16)v.z; u.h[3] = (f16)v.w;
  } else {
    u.h[0] = u.h[1] = u.h[2] = u.h[3] = (f16)0.0f;
  }
  *(uint2*)(wo + e) = u.q;
}

__global__ void kcvt_rw(const float* __restrict__ rwsrc, f16* __restrict__ ro) {
  int e = (blockIdx.x * 256 + threadIdx.x) << 2;  // [128][576] out
  int row = e / 576, c0 = e - row * 576;
  union { uint2 q; f16 h[4]; } u;
#pragma unroll
  for (int i = 0; i < 4; ++i) {
    int c = c0 + i;
    float v = (row < 127 && c < 513) ? rwsrc[(size_t)row * 513 + c] : 0.0f;
    u.h[i] = (f16)v;
  }
  *(uint2*)(ro + e) = u.q;
}

// W_pack [32768][544] fp16: col<513 = W_leaf, col 513 = b_leaf, rest 0
__global__ void kcvt_wleaf(const float* __restrict__ wl, const float* __restrict__ bl,
                           f16* __restrict__ wo) {
  int e = (blockIdx.x * 256 + threadIdx.x) << 3;
  int row = e / 544, c0 = e - row * 544;
  const float* src = wl + (size_t)row * 513 + c0;
  F16x8U u;
#pragma unroll
  for (int i = 0; i < 8; ++i) {
    int c = c0 + i;
    float v = (c < 513) ? src[i] : ((c == 513) ? bl[row] : 0.0f);
    u.h[i] = (f16)v;
  }
  *(uint4*)(wo + e) = u.q;
}

// ---------------------------------------------------- generic 128x64 GEMM-BT
// MODE 0: h = relu(x@Wpre^T + b), f16 out stride 576, col513 := 1.0
// MODE 1: G = h@rw^T, f32 out stride 128
template <int MODE>
__global__ __launch_bounds__(256, 2) void kgemm(
    const f16* __restrict__ A, const f16* __restrict__ B,
    const float* __restrict__ bias, void* __restrict__ C,
    int NK, int astr, int bstr) {
  __shared__ alignas(16) f16 al[2][128 * 32];
  __shared__ alignas(16) f16 bl[2][64 * 40];
  const int tid = threadIdx.x, lane = tid & 63, wid = tid >> 6;
  const int wm = wid >> 1, wn = wid & 1;
  const int brow = blockIdx.x << 7, bcol = blockIdx.y << 6;

  int arow[2], aseg[2];
#pragma unroll
  for (int i = 0; i < 2; ++i) { int c = i * 256 + tid; arow[i] = c >> 2; aseg[i] = c & 3; }
  int br0 = tid / 5, bs0 = tid - br0 * 5;
  int c1 = 256 + lane;
  int br1 = c1 / 5, bs1 = c1 - br1 * 5;

  f32x4 acc[4][2];
#pragma unroll
  for (int mf = 0; mf < 4; ++mf)
#pragma unroll
    for (int nf = 0; nf < 2; ++nf)
#pragma unroll
      for (int j = 0; j < 4; ++j) acc[mf][nf][j] = 0.0f;

  auto stage = [&](int kc, int bf) {
    int kcol = kc << 5;
#pragma unroll
    for (int i = 0; i < 2; ++i) {
      f16* ldsb = &al[bf][(i * 256 + (wid << 6)) << 3];
      GLD16(A + (size_t)(brow + arow[i]) * astr + kcol + (aseg[i] << 3), ldsb);
    }
    {
      f16* ldsb = &bl[bf][(wid << 6) << 3];
      GLD16(B + (size_t)(bcol + br0) * bstr + kcol + (bs0 < 4 ? (bs0 << 3) : 0), ldsb);
    }
    if (wid == 0) {
      f16* ldsb = &bl[bf][256 << 3];
      GLD16(B + (size_t)(bcol + br1) * bstr + kcol + (bs1 < 4 ? (bs1 << 3) : 0), ldsb);
    }
  };

  stage(0, 0);
  __syncthreads();
  int cur = 0;
  for (int kc = 0; kc < NK; ++kc) {
    if (kc + 1 < NK) stage(kc + 1, cur ^ 1);
    f16x8 af[4], bfm[2];
#pragma unroll
    for (int mf = 0; mf < 4; ++mf)
      af[mf] = *(const f16x8*)&al[cur][((wm << 6) + (mf << 4) + (lane & 15)) * 32 + ((lane >> 4) << 3)];
#pragma unroll
    for (int nf = 0; nf < 2; ++nf)
      bfm[nf] = *(const f16x8*)&bl[cur][((wn << 5) + (nf << 4) + (lane & 15)) * 40 + ((lane >> 4) << 3)];
#pragma unroll
    for (int mf = 0; mf < 4; ++mf)
#pragma unroll
      for (int nf = 0; nf < 2; ++nf)
        acc[mf][nf] = __builtin_amdgcn_mfma_f32_16x16x32_f16(af[mf], bfm[nf], acc[mf][nf], 0, 0, 0);
    __syncthreads();
    cur ^= 1;
  }

#pragma unroll
  for (int mf = 0; mf < 4; ++mf) {
#pragma unroll
    for (int nf = 0; nf < 2; ++nf) {
      int gcol = bcol + (wn << 5) + (nf << 4) + (lane & 15);
      int gr0 = brow + (wm << 6) + (mf << 4) + ((lane >> 4) << 2);
      if (MODE == 0) {
        float bv = (gcol < 513) ? bias[gcol] : 0.0f;
#pragma unroll
        for (int j = 0; j < 4; ++j) {
          float v = fmaxf(acc[mf][nf][j] + bv, 0.0f);
          ((f16*)C)[(size_t)(gr0 + j) * 576 + gcol] = (gcol == 513) ? (f16)1.0f : (f16)v;
        }
      } else {
#pragma unroll
        for (int j = 0; j < 4; ++j)
          ((float*)C)[(size_t)(gr0 + j) * 128 + gcol] = acc[mf][nf][j];
      }
    }
  }
}

// ---------------------------------------------------------------- norms
__global__ void khnorm(const f16* __restrict__ hf, float* __restrict__ ihn) {
  int row = (blockIdx.x << 2) + (threadIdx.x >> 6);
  int lane = threadIdx.x & 63;
  float s = 0.0f;
  for (int c = lane; c < 513; c += 64) {
    float v = (float)hf[(size_t)row * 576 + c];
    s += v * v;
  }
  for (int o = 32; o; o >>= 1) s += __shfl_down(s, o);
  if (!lane) ihn[row] = 1.0f / fmaxf(sqrtf(s), 1e-12f);
}

__global__ void kinvrw(const float* __restrict__ rw, float* __restrict__ irw) {
  int j = (blockIdx.x << 2) + (threadIdx.x >> 6);
  if (j >= 127) return;
  int lane = threadIdx.x & 63;
  float s = 0.0f;
  for (int d = lane; d < 513; d += 64) {
    float v = rw[(size_t)j * 513 + d];
    s += v * v;
  }
  for (int o = 32; o; o >>= 1) s += __shfl_down(s, o);
  if (!lane) irw[j] = 1.0f / fmaxf(sqrtf(s), 1e-12f);
}

// ------------------------------------------------------------- routing/softmax
// per-sample tree walk; writes s_w as fp16 in block-permuted layout
// swh[l*8192 + (b&~127) + ((b&15)<<3) + ((b>>4)&7)]
__global__ void kroute(const float* __restrict__ G, const float* __restrict__ ihn,
                       const float* __restrict__ irw, u16* __restrict__ swh,
                       float* __restrict__ entp) {
  int b = blockIdx.x * 256 + threadIdx.x;
  float ih = ihn[b];
  const float* g = G + (size_t)b * 128;
  float ent = 0.0f;
  size_t wbase = (size_t)(b & ~127) + (((size_t)b & 15) << 3) + ((b >> 4) & 7);
  for (int l = 0; l < 128; ++l) {
    int n = 0;
    float lp = 0.0f;
#pragma unroll
    for (int k = 6; k >= 0; --k) {
      int bit = (l >> k) & 1;
      float cs = g[n] * ih * irw[n];
      float pr = bit ? 0.5f * (1.0f - cs) : 0.5f * (1.0f + cs);
      pr = fminf(fmaxf(pr, 0.01f), 0.99f);
      lp += __logf(pr);
      n = 2 * n + 1 + bit;
    }
    float sw = __expf(lp);
    ent -= sw * lp;
    HBits hb; hb.f = (f16)sw;
    swh[(size_t)l * 8192 + wbase] = hb.u;
  }
  for (int o = 32; o; o >>= 1) ent += __shfl_down(ent, o);
  __shared__ float red[4];
  if (!(threadIdx.x & 63)) red[threadIdx.x >> 6] = ent;
  __syncthreads();
  if (!threadIdx.x) atomicAdd(entp, red[0] + red[1] + red[2] + red[3]);
}

// ------------------------------------------------------------------ big GEMM
// out[b,o] = scale * sum_l sum_k (s_w[l,b]*h[b,k]) * Wpack[l*256+o, k]
// v2: 512 thr = 8 waves (wm2 x wn2 x leafhalf2); wave tile M64(MF4) x N32(NF2),
// 2 leaves/step. A in regs per k-chunk; B 4-buffer (stage s+2), counted
// vmcnt(4), ONE s_barrier/step; XOR source-swizzle on B staging; epilogue
// LDS-reduce across leaf halves.
__global__ __launch_bounds__(512, 2) void kbig(
    const f16* __restrict__ hf, const f16* __restrict__ wp,
    const u16* __restrict__ swh, const float* __restrict__ entp,
    float* __restrict__ out) {
  __shared__ alignas(16) u16 slds[16384];       // 32 KB s_w (permuted)
  __shared__ alignas(16) f16 blds[4][8192];     // 4 x 16 KB B buffers

  const int tid = threadIdx.x;
  const int lane = tid & 63, wid = tid >> 6;
  const int lh = wid >> 2;          // leaf half (0/1)
  const int wm = (wid >> 1) & 1;    // M half (64 rows)
  const int wn = wid & 1;           // N half (32 cols)

  const int d = blockIdx.x;         // XCD-aware: 2 XCDs per o-tile
  const int ob = (d >> 1) & 3;
  const int mb = ((d & 1) << 5) | (d >> 3);
  const int brow = mb << 7;
  const int ocol = ob << 6;

  // ---- stage s_w slab: 2048 x 16B chunks, 4/thread, linear
#pragma unroll
  for (int i = 0; i < 4; ++i) {
    int c = i * 512 + tid;
    int l = c >> 4, q = (c & 15) << 3;
    GLD16(swh + ((size_t)l << 13) + brow + q, slds + ((i * 512 + (wid << 6)) << 3));
  }

  // ---- B stage: 1024 chunks/step, 2/thread; source XOR-swizzled (T2/m173)
  int pb[2];
#pragma unroll
  for (int i = 0; i < 2; ++i) {
    int c = i * 512 + tid;
    int leaf = c >> 8, r = (c >> 2) & 63, sl = c & 3;
    int ss = sl ^ ((r >> 2) & 3);
    pb[i] = (leaf * 256 + ocol + r) * 544 + (ss << 3);
  }
  auto stageB = [&](int s) {
    const f16* src = wp + (size_t)(s & 31) * 557056 + ((s >> 5) << 5);
    f16* bb = blds[s & 3];
#pragma unroll
    for (int i = 0; i < 2; ++i)
      GLD16(src + pb[i], bb + ((i * 512 + (wid << 6)) << 3));
  };

  stageB(0);
  stageB(1);

  f32x4 acc[4][2];
#pragma unroll
  for (int mf = 0; mf < 4; ++mf)
#pragma unroll
    for (int nf = 0; nf < 2; ++nf)
#pragma unroll
      for (int j = 0; j < 4; ++j) acc[mf][nf][j] = 0.0f;

  f16x8 afr[4];
  const f16* abase = hf + (size_t)(brow + (wm << 6) + (lane & 15)) * 576 + ((lane >> 4) << 3);
  int boff[2];
#pragma unroll
  for (int nf = 0; nf < 2; ++nf) {
    int r = (wn << 5) + (nf << 4) + (lane & 15);
    int s4 = (lane >> 4) ^ ((r >> 2) & 3);
    boff[nf] = (r << 5) + (s4 << 3);
  }
  const int soff = ((lane & 15) << 3) + (wm << 2);  // u16 units within 128-entry l-row

  for (int s = 0; s < 544; ++s) {
    const int kc = s >> 5, lg = s & 31;
    if (lg == 0) {  // A fragments for this k-chunk (regs, reused 32 steps)
      const f16* ap = abase + (kc << 5);
#pragma unroll
      for (int mf = 0; mf < 4; ++mf)
        afr[mf] = *(const f16x8*)(ap + (size_t)(mf << 4) * 576);
    }
    __builtin_amdgcn_sched_barrier(0);  // pin A-loads before stage (vmcnt order)
    if (s + 2 < 544) stageB(s + 2);
    __builtin_amdgcn_sched_barrier(0);
    if (s + 2 < 544)      asm volatile("s_waitcnt vmcnt(4)" ::: "memory");
    else if (s == 542)    asm volatile("s_waitcnt vmcnt(2)" ::: "memory");
    else                  asm volatile("s_waitcnt vmcnt(0)" ::: "memory");
    __builtin_amdgcn_s_barrier();
    __builtin_amdgcn_sched_barrier(0);

    const f16* bb = blds[s & 3];
    __builtin_amdgcn_s_setprio(1);
#pragma unroll
    for (int ls = 0; ls < 2; ++ls) {
      const int l = (lg << 2) + (lh << 1) + ls;
      uint2 sq = *(const uint2*)(slds + (l << 7) + soff);
      const f16* bl0 = bb + ((l & 3) << 11);
      f16x8 bfr0 = *(const f16x8*)(bl0 + boff[0]);
      f16x8 bfr1 = *(const f16x8*)(bl0 + boff[1]);
      u16 sc[4] = {(u16)(sq.x & 0xffffu), (u16)(sq.x >> 16),
                   (u16)(sq.y & 0xffffu), (u16)(sq.y >> 16)};
#pragma unroll
      for (int mf = 0; mf < 4; ++mf) {
        HBits hb; hb.u = sc[mf];
        f16x8 as = afr[mf] * hb.f;  // fold s_w[l,row] into A fragment
        acc[mf][0] = __builtin_amdgcn_mfma_f32_16x16x32_f16(as, bfr0, acc[mf][0], 0, 0, 0);
        acc[mf][1] = __builtin_amdgcn_mfma_f32_16x16x32_f16(as, bfr1, acc[mf][1], 0, 0, 0);
      }
    }
    __builtin_amdgcn_s_setprio(0);
    __builtin_amdgcn_sched_barrier(0);
  }

  // ---- epilogue: combine leaf halves via LDS (stride 36 to dodge bank 0)
  float* rb = (float*)&blds[0][0];
  const int p = (wm << 1) | wn;
  if (lh == 1) {
    float* wbase = rb + ((p << 6) + lane) * 36;
#pragma unroll
    for (int mf = 0; mf < 4; ++mf)
#pragma unroll
      for (int nf = 0; nf < 2; ++nf)
        *(f32x4*)(wbase + (((mf << 1) + nf) << 2)) = acc[mf][nf];
  }
  __syncthreads();
  if (lh == 0) {
    const float* rbase = rb + ((p << 6) + lane) * 36;
    float ent = *entp;
    float scale = 1.0f + ent / (8192.0f * (128.0f / 6.0f) * logf(6.0f));
    const int cc0 = ocol + (wn << 5) + (lane & 15);
#pragma unroll
    for (int mf = 0; mf < 4; ++mf) {
#pragma unroll
      for (int nf = 0; nf < 2; ++nf) {
        f32x4 o = acc[mf][nf] + *(const f32x4*)(rbase + (((mf << 1) + nf) << 2));
        int r0 = brow + (wm << 6) + (mf << 4) + ((lane >> 4) << 2);
        int cc = cc0 + (nf << 4);
#pragma unroll
        for (int j = 0; j < 4; ++j)
          out[(size_t)(r0 + j) * 256 + cc] = scale * o[j];
      }
    }
  }
}

// ------------------------------------------------------------------- launch
extern "C" void kernel_launch(void* const* d_in, const int* in_sizes, int n_in,
                              void* d_out, int out_size, void* d_ws, size_t ws_size,
                              hipStream_t stream) {
  const float* x     = (const float*)d_in[0];
  const float* wpre  = (const float*)d_in[1];
  const float* bpre  = (const float*)d_in[2];
  const float* rw    = (const float*)d_in[3];
  const float* wleaf = (const float*)d_in[4];
  const float* bleaf = (const float*)d_in[5];
  float* out = (float*)d_out;

  char* ws = (char*)d_ws;
  constexpr size_t O_ENT = 0;
  constexpr size_t O_XO  = 256;                     // x fp16 [8192][512]
  constexpr size_t O_WPO = O_XO  + 8388608;         // Wpre fp16 [576][512]
  constexpr size_t O_RWO = O_WPO + 589824;          // rw fp16 [128][576]
  constexpr size_t O_IRW = O_RWO + 147456;          // 1/||rw|| [128]
  constexpr size_t O_HO  = O_IRW + 512;             // h fp16 [8192][576]
  constexpr size_t O_IHN = O_HO  + 9437184;         // 1/||h|| [8192]
  constexpr size_t O_G   = O_IHN + 32768;           // G f32 [8192][128]
  constexpr size_t O_SWH = O_G   + 4194304;         // s_w fp16 perm [128][8192]
  constexpr size_t O_WPK = O_SWH + 2097152;         // Wpack fp16 [32768][544]

  float* ent = (float*)(ws + O_ENT);
  f16* xo   = (f16*)(ws + O_XO);
  f16* wpo  = (f16*)(ws + O_WPO);
  f16* rwo  = (f16*)(ws + O_RWO);
  float* irw = (float*)(ws + O_IRW);
  f16* ho   = (f16*)(ws + O_HO);
  float* ihn = (float*)(ws + O_IHN);
  float* go = (float*)(ws + O_G);
  u16* swh  = (u16*)(ws + O_SWH);
  f16* wpk  = (f16*)(ws + O_WPK);

  hipMemsetAsync(ent, 0, sizeof(float), stream);
  kcvt_x<<<2048, 256, 0, stream>>>(x, xo);
  kcvt_wpre<<<288, 256, 0, stream>>>(wpre, wpo);
  kcvt_rw<<<72, 256, 0, stream>>>(rw, rwo);
  kcvt_wleaf<<<8704, 256, 0, stream>>>(wleaf, bleaf, wpk);
  kgemm<0><<<dim3(64, 9), 256, 0, stream>>>(xo, wpo, bpre, (void*)ho, 16, 512, 512);
  khnorm<<<2048, 256, 0, stream>>>(ho, ihn);
  kinvrw<<<32, 256, 0, stream>>>(rw, irw);
  kgemm<1><<<dim3(64, 2), 256, 0, stream>>>(ho, rwo, nullptr, (void*)go, 17, 576, 576);
  kroute<<<32, 256, 0, stream>>>(go, ihn, irw, swh, ent);
  kbig<<<256, 512, 0, stream>>>(ho, wpk, swh, ent, out);
}

// Round 3
// 654.458 us; speedup vs baseline: 1.4850x; 1.0564x over previous
//
#include <hip/hip_runtime.h>

typedef _Float16 f16;
typedef unsigned short u16;
typedef unsigned int u32;
typedef _Float16 f16x8 __attribute__((ext_vector_type(8)));
typedef float f32x4 __attribute__((ext_vector_type(4)));
typedef float f32x16 __attribute__((ext_vector_type(16)));

union F16x8U { f16x8 v; uint4 q; u16 us[8]; f16 h[8]; };
union HBits { f16 f; u16 u; };

#define GLD16(g, l)                                                        \
  __builtin_amdgcn_global_load_lds(                                        \
      (const __attribute__((address_space(1))) void*)(g),                  \
      (__attribute__((address_space(3))) void*)(l), 16, 0, 0)

// ---------------------------------------------------------------- converts
// fused: blocks [0,2048) x-cvt, [2048,2336) wpre, [2336,2408) rw, rest wleaf
__global__ void kcvt_all(const float* __restrict__ x, f16* __restrict__ xo,
                         const float* __restrict__ w, f16* __restrict__ wo,
                         const float* __restrict__ rwsrc, f16* __restrict__ ro,
                         const float* __restrict__ wl, const float* __restrict__ blf,
                         f16* __restrict__ wpk) {
  int b = blockIdx.x;
  if (b < 2048) {                          // x: [8192][512] f32 -> f16
    int i = (b * 256 + threadIdx.x) << 3;
    float4 a = *(const float4*)(x + i);
    float4 c = *(const float4*)(x + i + 4);
    F16x8U u;
    u.h[0] = (f16)a.x; u.h[1] = (f16)a.y; u.h[2] = (f16)a.z; u.h[3] = (f16)a.w;
    u.h[4] = (f16)c.x; u.h[5] = (f16)c.y; u.h[6] = (f16)c.z; u.h[7] = (f16)c.w;
    *(uint4*)(xo + i) = u.q;
  } else if (b < 2336) {                   // W_pre -> [576][512] f16 (pad rows 0)
    int e = ((b - 2048) * 256 + threadIdx.x) << 2;
    int row = e >> 9, col = e & 511;
    union { uint2 q; f16 h[4]; } u;
    if (row < 513) {
      float4 v = *(const float4*)(w + (size_t)row * 512 + col);
      u.h[0] = (f16)v.x; u.h[1] = (f16)v.y; u.h[2] = (f16)v.z; u.h[3] = (f16)v.w;
    } else {
      u.h[0] = u.h[1] = u.h[2] = u.h[3] = (f16)0.0f;
    }
    *(uint2*)(wo + e) = u.q;
  } else if (b < 2408) {                   // right_w -> [128][576] f16
    int e = ((b - 2336) * 256 + threadIdx.x) << 2;
    int row = e / 576, c0 = e - row * 576;
    union { uint2 q; f16 h[4]; } u;
#pragma unroll
    for (int i = 0; i < 4; ++i) {
      int c = c0 + i;
      float v = (row < 127 && c < 513) ? rwsrc[(size_t)row * 513 + c] : 0.0f;
      u.h[i] = (f16)v;
    }
    *(uint2*)(ro + e) = u.q;
  } else {                                 // W_pack [32768][544]: W_leaf|b|0
    int e = ((b - 2408) * 256 + threadIdx.x) << 3;
    int row = e / 544, c0 = e - row * 544;
    const float* src = wl + (size_t)row * 513 + c0;
    F16x8U u;
#pragma unroll
    for (int i = 0; i < 8; ++i) {
      int c = c0 + i;
      float v = (c < 513) ? src[i] : ((c == 513) ? blf[row] : 0.0f);
      u.h[i] = (f16)v;
    }
    *(uint4*)(wpk + e) = u.q;
  }
}

// ---------------------------------------------------- generic 128x64 GEMM-BT
template <int MODE>
__global__ __launch_bounds__(256, 2) void kgemm(
    const f16* __restrict__ A, const f16* __restrict__ B,
    const float* __restrict__ bias, void* __restrict__ C,
    int NK, int astr, int bstr) {
  __shared__ alignas(16) f16 al[2][128 * 32];
  __shared__ alignas(16) f16 bl[2][64 * 40];
  const int tid = threadIdx.x, lane = tid & 63, wid = tid >> 6;
  const int wm = wid >> 1, wn = wid & 1;
  const int brow = blockIdx.x << 7, bcol = blockIdx.y << 6;

  int arow[2], aseg[2];
#pragma unroll
  for (int i = 0; i < 2; ++i) { int c = i * 256 + tid; arow[i] = c >> 2; aseg[i] = c & 3; }
  int br0 = tid / 5, bs0 = tid - br0 * 5;
  int c1 = 256 + lane;
  int br1 = c1 / 5, bs1 = c1 - br1 * 5;

  f32x4 acc[4][2];
#pragma unroll
  for (int mf = 0; mf < 4; ++mf)
#pragma unroll
    for (int nf = 0; nf < 2; ++nf)
#pragma unroll
      for (int j = 0; j < 4; ++j) acc[mf][nf][j] = 0.0f;

  auto stage = [&](int kc, int bf) {
    int kcol = kc << 5;
#pragma unroll
    for (int i = 0; i < 2; ++i) {
      f16* ldsb = &al[bf][(i * 256 + (wid << 6)) << 3];
      GLD16(A + (size_t)(brow + arow[i]) * astr + kcol + (aseg[i] << 3), ldsb);
    }
    {
      f16* ldsb = &bl[bf][(wid << 6) << 3];
      GLD16(B + (size_t)(bcol + br0) * bstr + kcol + (bs0 < 4 ? (bs0 << 3) : 0), ldsb);
    }
    if (wid == 0) {
      f16* ldsb = &bl[bf][256 << 3];
      GLD16(B + (size_t)(bcol + br1) * bstr + kcol + (bs1 < 4 ? (bs1 << 3) : 0), ldsb);
    }
  };

  stage(0, 0);
  __syncthreads();
  int cur = 0;
  for (int kc = 0; kc < NK; ++kc) {
    if (kc + 1 < NK) stage(kc + 1, cur ^ 1);
    f16x8 af[4], bfm[2];
#pragma unroll
    for (int mf = 0; mf < 4; ++mf)
      af[mf] = *(const f16x8*)&al[cur][((wm << 6) + (mf << 4) + (lane & 15)) * 32 + ((lane >> 4) << 3)];
#pragma unroll
    for (int nf = 0; nf < 2; ++nf)
      bfm[nf] = *(const f16x8*)&bl[cur][((wn << 5) + (nf << 4) + (lane & 15)) * 40 + ((lane >> 4) << 3)];
#pragma unroll
    for (int mf = 0; mf < 4; ++mf)
#pragma unroll
      for (int nf = 0; nf < 2; ++nf)
        acc[mf][nf] = __builtin_amdgcn_mfma_f32_16x16x32_f16(af[mf], bfm[nf], acc[mf][nf], 0, 0, 0);
    __syncthreads();
    cur ^= 1;
  }

#pragma unroll
  for (int mf = 0; mf < 4; ++mf) {
#pragma unroll
    for (int nf = 0; nf < 2; ++nf) {
      int gcol = bcol + (wn << 5) + (nf << 4) + (lane & 15);
      int gr0 = brow + (wm << 6) + (mf << 4) + ((lane >> 4) << 2);
      if (MODE == 0) {
        float bv = (gcol < 513) ? bias[gcol] : 0.0f;
#pragma unroll
        for (int j = 0; j < 4; ++j) {
          float v = fmaxf(acc[mf][nf][j] + bv, 0.0f);
          ((f16*)C)[(size_t)(gr0 + j) * 576 + gcol] = (gcol == 513) ? (f16)1.0f : (f16)v;
        }
      } else {
#pragma unroll
        for (int j = 0; j < 4; ++j)
          ((float*)C)[(size_t)(gr0 + j) * 128 + gcol] = acc[mf][nf][j];
      }
    }
  }
}

// ---------------------------------------------------------------- norms
__global__ void khnorm(const f16* __restrict__ hf, float* __restrict__ ihn) {
  int row = (blockIdx.x << 2) + (threadIdx.x >> 6);
  int lane = threadIdx.x & 63;
  float s = 0.0f;
  for (int c = lane; c < 513; c += 64) {
    float v = (float)hf[(size_t)row * 576 + c];
    s += v * v;
  }
  for (int o = 32; o; o >>= 1) s += __shfl_down(s, o);
  if (!lane) ihn[row] = 1.0f / fmaxf(sqrtf(s), 1e-12f);
}

__global__ void kinvrw(const float* __restrict__ rw, float* __restrict__ irw) {
  int j = (blockIdx.x << 2) + (threadIdx.x >> 6);
  if (j >= 127) return;
  int lane = threadIdx.x & 63;
  float s = 0.0f;
  for (int d = lane; d < 513; d += 64) {
    float v = rw[(size_t)j * 513 + d];
    s += v * v;
  }
  for (int o = 32; o; o >>= 1) s += __shfl_down(s, o);
  if (!lane) irw[j] = 1.0f / fmaxf(sqrtf(s), 1e-12f);
}

// ------------------------------------------------------------- routing/softmax
// s_w global layout (u16): idx = l*8192 + (b&~127) + ((b&31)>>1)*8 + (b&1)*4 + ((b>>5)&3)
// (so kbig can stage 16B chunks that land as [l][r 0..31][p 0..3], row = r+32p)
__global__ void kroute(const float* __restrict__ G, const float* __restrict__ ihn,
                       const float* __restrict__ irw, u16* __restrict__ swh,
                       float* __restrict__ entp) {
  int b = blockIdx.x * 256 + threadIdx.x;
  float ih = ihn[b];
  const float* g = G + (size_t)b * 128;
  float ent = 0.0f;
  size_t wbase = (size_t)(b & ~127) + (((b & 31) >> 1) << 3) + ((b & 1) << 2) + ((b >> 5) & 3);
  for (int l = 0; l < 128; ++l) {
    int n = 0;
    float lp = 0.0f;
#pragma unroll
    for (int k = 6; k >= 0; --k) {
      int bit = (l >> k) & 1;
      float cs = g[n] * ih * irw[n];
      float pr = bit ? 0.5f * (1.0f - cs) : 0.5f * (1.0f + cs);
      pr = fminf(fmaxf(pr, 0.01f), 0.99f);
      lp += __logf(pr);
      n = 2 * n + 1 + bit;
    }
    float sw = __expf(lp);
    ent -= sw * lp;
    HBits hb; hb.f = (f16)sw;
    swh[(size_t)l * 8192 + wbase] = hb.u;
  }
  for (int o = 32; o; o >>= 1) ent += __shfl_down(ent, o);
  __shared__ float red[4];
  if (!(threadIdx.x & 63)) red[threadIdx.x >> 6] = ent;
  __syncthreads();
  if (!threadIdx.x) atomicAdd(entp, red[0] + red[1] + red[2] + red[3]);
}

// ------------------------------------------------------------------ big GEMM
// out[b,o] = scale * sum_l sum_k (s_w[l,b]*h[b,k]) * Wpack[l*256+o, k]
// v3: 32x32x16 MFMA, MF4 (wave = all 128 rows x 32 cols), 8-way leaf split,
// 2 blocks/CU (72KB LDS, <=128 VGPR). Step = 8 leaves x 16 k, 544 steps.
// One s_barrier/step, counted vmcnt (2 / 3), NB=4 B-bufs stage-ahead 2,
// A staged to LDS per 16-k chunk (dbuf). Epilogue: 3-round LDS tree reduce.
__global__ __launch_bounds__(512, 4) void kbig(
    const f16* __restrict__ hf, const f16* __restrict__ wp,
    const u16* __restrict__ swh, const float* __restrict__ entp,
    float* __restrict__ out) {
  __shared__ alignas(16) char smem[73728];  // 32K s_w | 32K B(4x8K) | 8K A(2x4K)

  const int tid = threadIdx.x, lane = tid & 63, wid = tid >> 6;
  const int obl = blockIdx.x & 7, mb = blockIdx.x >> 3;  // obl = XCD id
  const int brow = mb << 7, ocol = obl << 5;

  // ---- prologue: s_w slab (2048 slots), A chunk 0, B steps 0,1
#pragma unroll
  for (int i = 0; i < 4; ++i) {
    int c = i * 512 + tid;
    int l = c >> 4, rg = c & 15;
    GLD16(swh + (size_t)l * 8192 + mb * 128 + rg * 8,
          smem + ((i * 512 + (wid << 6)) << 4));
  }
  auto stageA = [&](int kcp) {
    int c = tid & 255, q = c >> 7, row = c & 127;
    GLD16(hf + (size_t)(brow + row) * 576 + kcp * 16 + q * 8,
          smem + 65536 + ((kcp & 1) << 12) + ((wid & 3) << 10));
  };
  auto stageB = [&](int s2) {
    int kcp = s2 >> 4, lgp = s2 & 15;
    int col = lane & 31, q = (lane >> 5) & 1;
    GLD16(wp + (size_t)((lgp * 8 + wid) * 256 + ocol + col) * 544 + kcp * 16 + q * 8,
          smem + 32768 + ((s2 & 3) << 13) + (wid << 10));
  };
  stageA(0);
  stageB(0);
  stageB(1);

  f32x16 acc[4];
#pragma unroll
  for (int mf = 0; mf < 4; ++mf)
#pragma unroll
    for (int j = 0; j < 16; ++j) acc[mf][j] = 0.0f;

  f16x8 afr[4];
  const int aoff = 65536 + ((lane >> 5) << 11) + ((lane & 31) << 4);  // + mf*512
  const int boff = 32768 + (wid << 10) + ((lane >> 5) << 9) + ((lane & 31) << 4);
  const int swoff = ((lane & 31) << 3);  // + l*256

  // ---- main loop: kc 0..32 (full), then kc 33 tail
  for (int kc = 0; kc < 33; ++kc) {
#pragma unroll
    for (int lg = 0; lg < 16; ++lg) {
      const int s = kc * 16 + lg;
      stageB(s + 2);
      if (lg == 4) stageA(kc + 1);
      if (lg >= 4 && lg <= 6) asm volatile("s_waitcnt vmcnt(3)" ::: "memory");
      else                    asm volatile("s_waitcnt vmcnt(2)" ::: "memory");
      __builtin_amdgcn_s_barrier();
      __builtin_amdgcn_sched_barrier(0);
      if (lg == 0) {
#pragma unroll
        for (int mf = 0; mf < 4; ++mf)
          afr[mf] = *(const f16x8*)(smem + aoff + ((kc & 1) << 12) + (mf << 9));
      }
      const int l = lg * 8 + wid;
      uint2 swq = *(const uint2*)(smem + (l << 8) + swoff);
      f16x8 bfr = *(const f16x8*)(smem + boff + ((s & 3) << 13));
      const u16* sc = (const u16*)&swq;
      __builtin_amdgcn_s_setprio(1);
#pragma unroll
      for (int mf = 0; mf < 4; ++mf) {
        HBits hb; hb.u = sc[mf];
        f16x8 as = afr[mf] * hb.f;
        acc[mf] = __builtin_amdgcn_mfma_f32_32x32x16_f16(as, bfr, acc[mf], 0, 0, 0);
      }
      __builtin_amdgcn_s_setprio(0);
      __builtin_amdgcn_sched_barrier(0);
    }
  }
  {  // kc = 33 tail
    const int kc = 33;
#pragma unroll
    for (int lg = 0; lg < 16; ++lg) {
      const int s = kc * 16 + lg;
      if (lg <= 13) stageB(s + 2);
      if (lg <= 13)      asm volatile("s_waitcnt vmcnt(2)" ::: "memory");
      else if (lg == 14) asm volatile("s_waitcnt vmcnt(1)" ::: "memory");
      else               asm volatile("s_waitcnt vmcnt(0)" ::: "memory");
      __builtin_amdgcn_s_barrier();
      __builtin_amdgcn_sched_barrier(0);
      if (lg == 0) {
#pragma unroll
        for (int mf = 0; mf < 4; ++mf)
          afr[mf] = *(const f16x8*)(smem + aoff + ((kc & 1) << 12) + (mf << 9));
      }
      const int l = lg * 8 + wid;
      uint2 swq = *(const uint2*)(smem + (l << 8) + swoff);
      f16x8 bfr = *(const f16x8*)(smem + boff + ((s & 3) << 13));
      const u16* sc = (const u16*)&swq;
      __builtin_amdgcn_s_setprio(1);
#pragma unroll
      for (int mf = 0; mf < 4; ++mf) {
        HBits hb; hb.u = sc[mf];
        f16x8 as = afr[mf] * hb.f;
        acc[mf] = __builtin_amdgcn_mfma_f32_32x32x16_f16(as, bfr, acc[mf], 0, 0, 0);
      }
      __builtin_amdgcn_s_setprio(0);
      __builtin_amdgcn_sched_barrier(0);
    }
  }

  // ---- epilogue: 3-round tree reduction over 8 leaf-partials
  auto writeAcc = [&](char* base) {
#pragma unroll
    for (int mf = 0; mf < 4; ++mf)
#pragma unroll
      for (int rq = 0; rq < 4; ++rq)
        *(f32x4*)(base + ((((mf << 2) + rq) << 6) + lane) * 16) =
            ((const f32x4*)&acc[mf])[rq];
  };
  auto addAcc = [&](const char* base) {
#pragma unroll
    for (int mf = 0; mf < 4; ++mf)
#pragma unroll
      for (int rq = 0; rq < 4; ++rq) {
        f32x4 v = *(const f32x4*)(base + ((((mf << 2) + rq) << 6) + lane) * 16);
        ((f32x4*)&acc[mf])[rq] += v;
      }
  };
  if (wid >= 4) writeAcc(smem + ((wid - 4) << 14));
  __syncthreads();
  if (wid < 4) addAcc(smem + (wid << 14));
  __syncthreads();
  if (wid == 2 || wid == 3) writeAcc(smem + ((wid - 2) << 14));
  __syncthreads();
  if (wid < 2) addAcc(smem + (wid << 14));
  __syncthreads();
  if (wid == 1) writeAcc(smem);
  __syncthreads();
  if (wid == 0) {
    addAcc(smem);
    float scale = 1.0f + (*entp) / (8192.0f * (128.0f / 6.0f) * logf(6.0f));
#pragma unroll
    for (int mf = 0; mf < 4; ++mf)
#pragma unroll
      for (int r = 0; r < 16; ++r) {
        int row = brow + (mf << 5) + (r & 3) + ((r >> 2) << 3) + ((lane >> 5) << 2);
        out[(size_t)row * 256 + ocol + (lane & 31)] = scale * acc[mf][r];
      }
  }
}

// ------------------------------------------------------------------- launch
extern "C" void kernel_launch(void* const* d_in, const int* in_sizes, int n_in,
                              void* d_out, int out_size, void* d_ws, size_t ws_size,
                              hipStream_t stream) {
  const float* x     = (const float*)d_in[0];
  const float* wpre  = (const float*)d_in[1];
  const float* bpre  = (const float*)d_in[2];
  const float* rw    = (const float*)d_in[3];
  const float* wleaf = (const float*)d_in[4];
  const float* bleaf = (const float*)d_in[5];
  float* out = (float*)d_out;

  char* ws = (char*)d_ws;
  constexpr size_t O_ENT = 0;
  constexpr size_t O_XO  = 256;                     // x fp16 [8192][512]
  constexpr size_t O_WPO = O_XO  + 8388608;         // Wpre fp16 [576][512]
  constexpr size_t O_RWO = O_WPO + 589824;          // rw fp16 [128][576]
  constexpr size_t O_IRW = O_RWO + 147456;          // 1/||rw|| [128]
  constexpr size_t O_HO  = O_IRW + 512;             // h fp16 [8192][576]
  constexpr size_t O_IHN = O_HO  + 9437184;         // 1/||h|| [8192]
  constexpr size_t O_G   = O_IHN + 32768;           // G f32 [8192][128]
  constexpr size_t O_SWH = O_G   + 4194304;         // s_w fp16 perm [128][8192]
  constexpr size_t O_WPK = O_SWH + 2097152;         // Wpack fp16 [32768][544]

  float* ent = (float*)(ws + O_ENT);
  f16* xo   = (f16*)(ws + O_XO);
  f16* wpo  = (f16*)(ws + O_WPO);
  f16* rwo  = (f16*)(ws + O_RWO);
  float* irw = (float*)(ws + O_IRW);
  f16* ho   = (f16*)(ws + O_HO);
  float* ihn = (float*)(ws + O_IHN);
  float* go = (float*)(ws + O_G);
  u16* swh  = (u16*)(ws + O_SWH);
  f16* wpk  = (f16*)(ws + O_WPK);

  hipMemsetAsync(ent, 0, sizeof(float), stream);
  kcvt_all<<<11112, 256, 0, stream>>>(x, xo, wpre, wpo, rw, rwo, wleaf, bleaf, wpk);
  kgemm<0><<<dim3(64, 9), 256, 0, stream>>>(xo, wpo, bpre, (void*)ho, 16, 512, 512);
  khnorm<<<2048, 256, 0, stream>>>(ho, ihn);
  kinvrw<<<32, 256, 0, stream>>>(rw, irw);
  kgemm<1><<<dim3(64, 2), 256, 0, stream>>>(ho, rwo, nullptr, (void*)go, 17, 576, 576);
  kroute<<<32, 256, 0, stream>>>(go, ihn, irw, swh, ent);
  kbig<<<512, 512, 0, stream>>>(ho, wpk, swh, ent, out);
}

// Round 4
// 583.120 us; speedup vs baseline: 1.6667x; 1.1223x over previous
//
#include <hip/hip_runtime.h>

typedef _Float16 f16;
typedef unsigned short u16;
typedef unsigned int u32;
typedef _Float16 f16x8 __attribute__((ext_vector_type(8)));
typedef float f32x4 __attribute__((ext_vector_type(4)));
typedef float f32x16 __attribute__((ext_vector_type(16)));

union F16x8U { f16x8 v; uint4 q; u16 us[8]; f16 h[8]; };
union HBits { f16 f; u16 u; };

#define GLD16(g, l)                                                        \
  __builtin_amdgcn_global_load_lds(                                        \
      (const __attribute__((address_space(1))) void*)(g),                  \
      (__attribute__((address_space(3))) void*)(l), 16, 0, 0)

// ---------------------------------------------------------------- converts
// fused: blocks [0,2048) x-cvt, [2048,2336) wpre, [2336,2408) rw, rest wleaf
__global__ void kcvt_all(const float* __restrict__ x, f16* __restrict__ xo,
                         const float* __restrict__ w, f16* __restrict__ wo,
                         const float* __restrict__ rwsrc, f16* __restrict__ ro,
                         const float* __restrict__ wl, const float* __restrict__ blf,
                         f16* __restrict__ wpk) {
  int b = blockIdx.x;
  if (b < 2048) {                          // x: [8192][512] f32 -> f16
    int i = (b * 256 + threadIdx.x) << 3;
    float4 a = *(const float4*)(x + i);
    float4 c = *(const float4*)(x + i + 4);
    F16x8U u;
    u.h[0] = (f16)a.x; u.h[1] = (f16)a.y; u.h[2] = (f16)a.z; u.h[3] = (f16)a.w;
    u.h[4] = (f16)c.x; u.h[5] = (f16)c.y; u.h[6] = (f16)c.z; u.h[7] = (f16)c.w;
    *(uint4*)(xo + i) = u.q;
  } else if (b < 2336) {                   // W_pre -> [576][512] f16 (pad rows 0)
    int e = ((b - 2048) * 256 + threadIdx.x) << 2;
    int row = e >> 9, col = e & 511;
    union { uint2 q; f16 h[4]; } u;
    if (row < 513) {
      float4 v = *(const float4*)(w + (size_t)row * 512 + col);
      u.h[0] = (f16)v.x; u.h[1] = (f16)v.y; u.h[2] = (f16)v.z; u.h[3] = (f16)v.w;
    } else {
      u.h[0] = u.h[1] = u.h[2] = u.h[3] = (f16)0.0f;
    }
    *(uint2*)(wo + e) = u.q;
  } else if (b < 2408) {                   // right_w -> [128][576] f16
    int e = ((b - 2336) * 256 + threadIdx.x) << 2;
    int row = e / 576, c0 = e - row * 576;
    union { uint2 q; f16 h[4]; } u;
#pragma unroll
    for (int i = 0; i < 4; ++i) {
      int c = c0 + i;
      float v = (row < 127 && c < 513) ? rwsrc[(size_t)row * 513 + c] : 0.0f;
      u.h[i] = (f16)v;
    }
    *(uint2*)(ro + e) = u.q;
  } else {                                 // W_pack [32768][544]: W_leaf|b|0
    int e = ((b - 2408) * 256 + threadIdx.x) << 3;
    int row = e / 544, c0 = e - row * 544;
    const float* src = wl + (size_t)row * 513 + c0;
    F16x8U u;
#pragma unroll
    for (int i = 0; i < 8; ++i) {
      int c = c0 + i;
      float v = (c < 513) ? src[i] : ((c == 513) ? blf[row] : 0.0f);
      u.h[i] = (f16)v;
    }
    *(uint4*)(wpk + e) = u.q;
  }
}

// ---------------------------------------------------- generic 128x64 GEMM-BT
template <int MODE>
__global__ __launch_bounds__(256, 2) void kgemm(
    const f16* __restrict__ A, const f16* __restrict__ B,
    const float* __restrict__ bias, void* __restrict__ C,
    int NK, int astr, int bstr) {
  __shared__ alignas(16) f16 al[2][128 * 32];
  __shared__ alignas(16) f16 bl[2][64 * 40];
  const int tid = threadIdx.x, lane = tid & 63, wid = tid >> 6;
  const int wm = wid >> 1, wn = wid & 1;
  const int brow = blockIdx.x << 7, bcol = blockIdx.y << 6;

  int arow[2], aseg[2];
#pragma unroll
  for (int i = 0; i < 2; ++i) { int c = i * 256 + tid; arow[i] = c >> 2; aseg[i] = c & 3; }
  int br0 = tid / 5, bs0 = tid - br0 * 5;
  int c1 = 256 + lane;
  int br1 = c1 / 5, bs1 = c1 - br1 * 5;

  f32x4 acc[4][2];
#pragma unroll
  for (int mf = 0; mf < 4; ++mf)
#pragma unroll
    for (int nf = 0; nf < 2; ++nf)
#pragma unroll
      for (int j = 0; j < 4; ++j) acc[mf][nf][j] = 0.0f;

  auto stage = [&](int kc, int bf) {
    int kcol = kc << 5;
#pragma unroll
    for (int i = 0; i < 2; ++i) {
      f16* ldsb = &al[bf][(i * 256 + (wid << 6)) << 3];
      GLD16(A + (size_t)(brow + arow[i]) * astr + kcol + (aseg[i] << 3), ldsb);
    }
    {
      f16* ldsb = &bl[bf][(wid << 6) << 3];
      GLD16(B + (size_t)(bcol + br0) * bstr + kcol + (bs0 < 4 ? (bs0 << 3) : 0), ldsb);
    }
    if (wid == 0) {
      f16* ldsb = &bl[bf][256 << 3];
      GLD16(B + (size_t)(bcol + br1) * bstr + kcol + (bs1 < 4 ? (bs1 << 3) : 0), ldsb);
    }
  };

  stage(0, 0);
  __syncthreads();
  int cur = 0;
  for (int kc = 0; kc < NK; ++kc) {
    if (kc + 1 < NK) stage(kc + 1, cur ^ 1);
    f16x8 af[4], bfm[2];
#pragma unroll
    for (int mf = 0; mf < 4; ++mf)
      af[mf] = *(const f16x8*)&al[cur][((wm << 6) + (mf << 4) + (lane & 15)) * 32 + ((lane >> 4) << 3)];
#pragma unroll
    for (int nf = 0; nf < 2; ++nf)
      bfm[nf] = *(const f16x8*)&bl[cur][((wn << 5) + (nf << 4) + (lane & 15)) * 40 + ((lane >> 4) << 3)];
#pragma unroll
    for (int mf = 0; mf < 4; ++mf)
#pragma unroll
      for (int nf = 0; nf < 2; ++nf)
        acc[mf][nf] = __builtin_amdgcn_mfma_f32_16x16x32_f16(af[mf], bfm[nf], acc[mf][nf], 0, 0, 0);
    __syncthreads();
    cur ^= 1;
  }

#pragma unroll
  for (int mf = 0; mf < 4; ++mf) {
#pragma unroll
    for (int nf = 0; nf < 2; ++nf) {
      int gcol = bcol + (wn << 5) + (nf << 4) + (lane & 15);
      int gr0 = brow + (wm << 6) + (mf << 4) + ((lane >> 4) << 2);
      if (MODE == 0) {
        float bv = (gcol < 513) ? bias[gcol] : 0.0f;
#pragma unroll
        for (int j = 0; j < 4; ++j) {
          float v = fmaxf(acc[mf][nf][j] + bv, 0.0f);
          ((f16*)C)[(size_t)(gr0 + j) * 576 + gcol] = (gcol == 513) ? (f16)1.0f : (f16)v;
        }
      } else {
#pragma unroll
        for (int j = 0; j < 4; ++j)
          ((float*)C)[(size_t)(gr0 + j) * 128 + gcol] = acc[mf][nf][j];
      }
    }
  }
}

// ---------------------------------------------------------------- norms
__global__ void khnorm(const f16* __restrict__ hf, float* __restrict__ ihn) {
  int row = (blockIdx.x << 2) + (threadIdx.x >> 6);
  int lane = threadIdx.x & 63;
  float s = 0.0f;
  for (int c = lane; c < 513; c += 64) {
    float v = (float)hf[(size_t)row * 576 + c];
    s += v * v;
  }
  for (int o = 32; o; o >>= 1) s += __shfl_down(s, o);
  if (!lane) ihn[row] = 1.0f / fmaxf(sqrtf(s), 1e-12f);
}

__global__ void kinvrw(const float* __restrict__ rw, float* __restrict__ irw) {
  int j = (blockIdx.x << 2) + (threadIdx.x >> 6);
  if (j >= 127) return;
  int lane = threadIdx.x & 63;
  float s = 0.0f;
  for (int d = lane; d < 513; d += 64) {
    float v = rw[(size_t)j * 513 + d];
    s += v * v;
  }
  for (int o = 32; o; o >>= 1) s += __shfl_down(s, o);
  if (!lane) irw[j] = 1.0f / fmaxf(sqrtf(s), 1e-12f);
}

// ------------------------------------------------------------- routing/softmax
// s_w layout (u16): idx = l*8192 + (b&~127) + ((b&31)>>1)*8 + (b&1)*4 + ((b>>5)&3)
// v4: DFS over leaves — each tree edge evaluated exactly once (254 logs vs 896).
// Static stack indices (full d-unroll, uniform branches). grid 64 x 128.
__global__ void kroute(const float* __restrict__ G, const float* __restrict__ ihn,
                       const float* __restrict__ irw, u16* __restrict__ swh,
                       float* __restrict__ entp) {
  int b = blockIdx.x * 128 + threadIdx.x;
  float ih = ihn[b];
  const float* g = G + (size_t)b * 128;
  float ent = 0.0f;
  size_t wbase = (size_t)(b & ~127) + (((b & 31) >> 1) << 3) + ((b & 1) << 2) + ((b >> 5) & 3);
  float lp[8]; int nd[8];
  nd[0] = 0; lp[0] = 0.0f;
  for (int l = 0; l < 128; ++l) {
    int d0 = l ? (6 - __builtin_ctz(l)) : 0;   // uniform across the wave
#pragma unroll
    for (int d = 0; d < 7; ++d) {
      if (d >= d0) {
        int n = nd[d];
        int bit = (l >> (6 - d)) & 1;
        float cs = g[n] * ih * irw[n];
        float pr = bit ? 0.5f * (1.0f - cs) : 0.5f * (1.0f + cs);
        pr = fminf(fmaxf(pr, 0.01f), 0.99f);
        lp[d + 1] = lp[d] + __logf(pr);
        nd[d + 1] = 2 * n + 1 + bit;
      }
    }
    float sw = __expf(lp[7]);
    ent -= sw * lp[7];
    HBits hb; hb.f = (f16)sw;
    swh[(size_t)l * 8192 + wbase] = hb.u;
  }
  for (int o = 32; o; o >>= 1) ent += __shfl_down(ent, o);
  __shared__ float red[2];
  if (!(threadIdx.x & 63)) red[threadIdx.x >> 6] = ent;
  __syncthreads();
  if (!threadIdx.x) atomicAdd(entp, red[0] + red[1]);
}

// ------------------------------------------------------------------ big GEMM
// out[b,o] = scale * sum_l sum_k (s_w[l,b]*h[b,k]) * Wpack[l*256+o, k]
// v4: period = 2 steps per barrier (8 MFMA/wave/period), 264 periods, 528 steps
// (K cols 528..543 are zero padding — dropped). Both steps' LDS->reg loads
// issued before the first MFMA batch. NB=4 B-bufs, counted vmcnt, static
// offsets via pp-unroll. Epilogue: 3-round LDS tree reduce.
__global__ __launch_bounds__(512, 4) void kbig(
    const f16* __restrict__ hf, const f16* __restrict__ wp,
    const u16* __restrict__ swh, const float* __restrict__ entp,
    float* __restrict__ out) {
  __shared__ alignas(16) char smem[73728];  // 32K s_w | 32K B(4x8K) | 8K A(2x4K)

  const int tid = threadIdx.x, lane = tid & 63, wid = tid >> 6;
  const int obl = blockIdx.x & 7, mb = blockIdx.x >> 3;  // obl = XCD id
  const int brow = mb << 7, ocol = obl << 5;

  // ---- prologue: s_w slab (2048 slots), A chunk 0, B steps 0,1
#pragma unroll
  for (int i = 0; i < 4; ++i) {
    int c = i * 512 + tid;
    int l = c >> 4, rg = c & 15;
    GLD16(swh + (size_t)l * 8192 + mb * 128 + rg * 8,
          smem + ((i * 512 + (wid << 6)) << 4));
  }
  auto stageA = [&](int kcp) {
    int c = tid & 255, q = c >> 7, row = c & 127;
    GLD16(hf + (size_t)(brow + row) * 576 + kcp * 16 + q * 8,
          smem + 65536 + ((kcp & 1) << 12) + ((wid & 3) << 10));
  };
  auto stageB = [&](int s2) {
    int kcp = s2 >> 4, lgp = s2 & 15;
    int col = lane & 31, q = (lane >> 5) & 1;
    GLD16(wp + (size_t)((lgp * 8 + wid) * 256 + ocol + col) * 544 + kcp * 16 + q * 8,
          smem + 32768 + ((s2 & 3) << 13) + (wid << 10));
  };
  stageA(0);
  stageB(0);
  stageB(1);

  f32x16 acc[4];
#pragma unroll
  for (int mf = 0; mf < 4; ++mf)
#pragma unroll
    for (int j = 0; j < 16; ++j) acc[mf][j] = 0.0f;

  f16x8 afr[4];
  const int aoff = 65536 + ((lane >> 5) << 11) + ((lane & 31) << 4);  // + mf*512
  const int boffc = 32768 + (wid << 10) + ((lane >> 5) << 9) + ((lane & 31) << 4);
  const int swoff = (lane & 31) << 3;

  // ---- main loop: 33 k-chunks x 8 periods; period = steps {2p, 2p+1}
  for (int kc8 = 0; kc8 < 33; ++kc8) {
    const bool tail = (kc8 == 32);
#pragma unroll
    for (int pp = 0; pp < 8; ++pp) {
      const int p = kc8 * 8 + pp;
      const int s0 = 2 * p;
      if (!tail || pp < 7) { stageB(s0 + 2); stageB(s0 + 3); }
      if (pp == 4 && !tail) stageA(kc8 + 1);
      if (tail && pp == 7)         asm volatile("s_waitcnt vmcnt(0)" ::: "memory");
      else if (pp == 4 || pp == 5) asm volatile("s_waitcnt vmcnt(3)" ::: "memory");
      else                         asm volatile("s_waitcnt vmcnt(2)" ::: "memory");
      __builtin_amdgcn_s_barrier();
      __builtin_amdgcn_sched_barrier(0);
      if (pp == 0) {  // A fragments for this k-chunk (regs, reused 8 periods)
#pragma unroll
        for (int mf = 0; mf < 4; ++mf)
          afr[mf] = *(const f16x8*)(smem + aoff + ((kc8 & 1) << 12) + (mf << 9));
      }
      // both steps' LDS->reg loads up front (2nd batch latency hidden)
      const int bufA = (pp & 1) << 1;  // (2p)&3
      uint2 swqA = *(const uint2*)(smem + ((pp * 16 + wid) << 8) + swoff);
      f16x8 bfA = *(const f16x8*)(smem + boffc + (bufA << 13));
      uint2 swqB = *(const uint2*)(smem + ((pp * 16 + 8 + wid) << 8) + swoff);
      f16x8 bfB = *(const f16x8*)(smem + boffc + ((bufA + 1) << 13));
      __builtin_amdgcn_s_setprio(1);
      {
        const u16* sc = (const u16*)&swqA;
#pragma unroll
        for (int mf = 0; mf < 4; ++mf) {
          HBits hb; hb.u = sc[mf];
          f16x8 as = afr[mf] * hb.f;
          acc[mf] = __builtin_amdgcn_mfma_f32_32x32x16_f16(as, bfA, acc[mf], 0, 0, 0);
        }
      }
      {
        const u16* sc = (const u16*)&swqB;
#pragma unroll
        for (int mf = 0; mf < 4; ++mf) {
          HBits hb; hb.u = sc[mf];
          f16x8 as = afr[mf] * hb.f;
          acc[mf] = __builtin_amdgcn_mfma_f32_32x32x16_f16(as, bfB, acc[mf], 0, 0, 0);
        }
      }
      __builtin_amdgcn_s_setprio(0);
      __builtin_amdgcn_sched_barrier(0);
    }
  }

  // ---- epilogue: 3-round tree reduction over 8 leaf-partials
  __syncthreads();  // all waves done reading slds/B bufs before reuse
  auto writeAcc = [&](char* base) {
#pragma unroll
    for (int mf = 0; mf < 4; ++mf)
#pragma unroll
      for (int rq = 0; rq < 4; ++rq)
        *(f32x4*)(base + ((((mf << 2) + rq) << 6) + lane) * 16) =
            ((const f32x4*)&acc[mf])[rq];
  };
  auto addAcc = [&](const char* base) {
#pragma unroll
    for (int mf = 0; mf < 4; ++mf)
#pragma unroll
      for (int rq = 0; rq < 4; ++rq) {
        f32x4 v = *(const f32x4*)(base + ((((mf << 2) + rq) << 6) + lane) * 16);
        ((f32x4*)&acc[mf])[rq] += v;
      }
  };
  if (wid >= 4) writeAcc(smem + ((wid - 4) << 14));
  __syncthreads();
  if (wid < 4) addAcc(smem + (wid << 14));
  __syncthreads();
  if (wid == 2 || wid == 3) writeAcc(smem + ((wid - 2) << 14));
  __syncthreads();
  if (wid < 2) addAcc(smem + (wid << 14));
  __syncthreads();
  if (wid == 1) writeAcc(smem);
  __syncthreads();
  if (wid == 0) {
    addAcc(smem);
    float scale = 1.0f + (*entp) / (8192.0f * (128.0f / 6.0f) * logf(6.0f));
#pragma unroll
    for (int mf = 0; mf < 4; ++mf)
#pragma unroll
      for (int r = 0; r < 16; ++r) {
        int row = brow + (mf << 5) + (r & 3) + ((r >> 2) << 3) + ((lane >> 5) << 2);
        out[(size_t)row * 256 + ocol + (lane & 31)] = scale * acc[mf][r];
      }
  }
}

// ------------------------------------------------------------------- launch
extern "C" void kernel_launch(void* const* d_in, const int* in_sizes, int n_in,
                              void* d_out, int out_size, void* d_ws, size_t ws_size,
                              hipStream_t stream) {
  const float* x     = (const float*)d_in[0];
  const float* wpre  = (const float*)d_in[1];
  const float* bpre  = (const float*)d_in[2];
  const float* rw    = (const float*)d_in[3];
  const float* wleaf = (const float*)d_in[4];
  const float* bleaf = (const float*)d_in[5];
  float* out = (float*)d_out;

  char* ws = (char*)d_ws;
  constexpr size_t O_ENT = 0;
  constexpr size_t O_XO  = 256;                     // x fp16 [8192][512]
  constexpr size_t O_WPO = O_XO  + 8388608;         // Wpre fp16 [576][512]
  constexpr size_t O_RWO = O_WPO + 589824;          // rw fp16 [128][576]
  constexpr size_t O_IRW = O_RWO + 147456;          // 1/||rw|| [128]
  constexpr size_t O_HO  = O_IRW + 512;             // h fp16 [8192][576]
  constexpr size_t O_IHN = O_HO  + 9437184;         // 1/||h|| [8192]
  constexpr size_t O_G   = O_IHN + 32768;           // G f32 [8192][128]
  constexpr size_t O_SWH = O_G   + 4194304;         // s_w fp16 perm [128][8192]
  constexpr size_t O_WPK = O_SWH + 2097152;         // Wpack fp16 [32768][544]

  float* ent = (float*)(ws + O_ENT);
  f16* xo   = (f16*)(ws + O_XO);
  f16* wpo  = (f16*)(ws + O_WPO);
  f16* rwo  = (f16*)(ws + O_RWO);
  float* irw = (float*)(ws + O_IRW);
  f16* ho   = (f16*)(ws + O_HO);
  float* ihn = (float*)(ws + O_IHN);
  float* go = (float*)(ws + O_G);
  u16* swh  = (u16*)(ws + O_SWH);
  f16* wpk  = (f16*)(ws + O_WPK);

  hipMemsetAsync(ent, 0, sizeof(float), stream);
  kcvt_all<<<11112, 256, 0, stream>>>(x, xo, wpre, wpo, rw, rwo, wleaf, bleaf, wpk);
  kgemm<0><<<dim3(64, 9), 256, 0, stream>>>(xo, wpo, bpre, (void*)ho, 16, 512, 512);
  khnorm<<<2048, 256, 0, stream>>>(ho, ihn);
  kinvrw<<<32, 256, 0, stream>>>(rw, irw);
  kgemm<1><<<dim3(64, 2), 256, 0, stream>>>(ho, rwo, nullptr, (void*)go, 17, 576, 576);
  kroute<<<64, 128, 0, stream>>>(go, ihn, irw, swh, ent);
  kbig<<<512, 512, 0, stream>>>(ho, wpk, swh, ent, out);
}